// Round 15
// baseline (322.636 us; speedup 1.0000x reference)
//
#include <hip/hip_runtime.h>
#include <math.h>

#define BATCH 4096
#define T 128
#define HOR 24

#define LOG2E 1.44269504088896f
#define C2    2.88539008177793f   // 2*log2(e)

typedef _Float16 half2_t __attribute__((ext_vector_type(2)));
typedef _Float16 half8   __attribute__((ext_vector_type(8)));
typedef float f2  __attribute__((ext_vector_type(2)));
typedef float f4v __attribute__((ext_vector_type(4)));

__device__ __forceinline__ float fexp2(float x){ return __builtin_amdgcn_exp2f(x); }
__device__ __forceinline__ float frcp(float x){ return __builtin_amdgcn_rcpf(x); }
__device__ __forceinline__ float fsig(float x){ return frcp(1.0f + fexp2(-LOG2E*x)); }
__device__ __forceinline__ float ftanh(float x){ return fmaf(-2.0f, frcp(1.0f + fexp2(C2*x)), 1.0f); }
__device__ __forceinline__ half2_t bch(unsigned u){ return __builtin_bit_cast(half2_t,u); }
__device__ __forceinline__ unsigned pk2(float a,float b){ return __builtin_bit_cast(unsigned, __builtin_amdgcn_cvt_pkrtz(a,b)); }
__device__ __forceinline__ float fdot2f(half2_t a, half2_t b, float c){
#if __has_builtin(__builtin_amdgcn_fdot2)
  return __builtin_amdgcn_fdot2(a,b,c,false);
#else
  return fmaf((float)a.x,(float)b.x, fmaf((float)a.y,(float)b.y,c));
#endif
}
__device__ __forceinline__ f2 pkfma(f2 a, f2 b, f2 c){ return __builtin_elementwise_fma(a,b,c); }

template <int CTRL, int RMASK>
__device__ __forceinline__ float dpp_add(float v) {
  int s = __builtin_amdgcn_update_dpp(0, __builtin_bit_cast(int, v), CTRL, RMASK, 0xf, true);
  return v + __builtin_bit_cast(float, s);
}
__device__ __forceinline__ float wavesum_dpp(float v) {
  v = dpp_add<0x111, 0xf>(v);
  v = dpp_add<0x112, 0xf>(v);
  v = dpp_add<0x114, 0xf>(v);
  v = dpp_add<0x118, 0xf>(v);
  v = dpp_add<0x142, 0xa>(v);
  v = dpp_add<0x143, 0xc>(v);
  return v;                     // total in lane 63
}
__device__ __forceinline__ float rdl63(float v){
  return __builtin_bit_cast(float, __builtin_amdgcn_readlane(__builtin_bit_cast(int, v), 63));
}

__device__ __forceinline__ void gru_mv(const _Float16* hrow,
    const unsigned* wr_r, const unsigned* wr_z, const unsigned* wr_n,
    float& ar0, float& ar1, float& az0, float& az1, float& an0, float& an1)
{
  const uint4* hq = (const uint4*)hrow;
  #pragma unroll
  for (int q = 0; q < 8; ++q) {
    uint4 hv = hq[q];
    ar0 = fdot2f(bch(hv.x), bch(wr_r[4*q+0]), ar0);
    az0 = fdot2f(bch(hv.x), bch(wr_z[4*q+0]), az0);
    an0 = fdot2f(bch(hv.x), bch(wr_n[4*q+0]), an0);
    ar1 = fdot2f(bch(hv.y), bch(wr_r[4*q+1]), ar1);
    az1 = fdot2f(bch(hv.y), bch(wr_z[4*q+1]), az1);
    an1 = fdot2f(bch(hv.y), bch(wr_n[4*q+1]), an1);
    ar0 = fdot2f(bch(hv.z), bch(wr_r[4*q+2]), ar0);
    az0 = fdot2f(bch(hv.z), bch(wr_z[4*q+2]), az0);
    an0 = fdot2f(bch(hv.z), bch(wr_n[4*q+2]), an0);
    ar1 = fdot2f(bch(hv.w), bch(wr_r[4*q+3]), ar1);
    az1 = fdot2f(bch(hv.w), bch(wr_z[4*q+3]), az1);
    an1 = fdot2f(bch(hv.w), bch(wr_n[4*q+3]), an1);
  }
}

__device__ __forceinline__ float proj_dot(const _Float16* base, const unsigned* udr)
{
  float acc = 0.f;
  const uint4* hb = (const uint4*)base;
  #pragma unroll
  for (int q = 0; q < 4; ++q) {
    uint4 hv = hb[q];
    acc = fdot2f(bch(hv.x), bch(udr[4*q+0]), acc);
    acc = fdot2f(bch(hv.y), bch(udr[4*q+1]), acc);
    acc = fdot2f(bch(hv.z), bch(udr[4*q+2]), acc);
    acc = fdot2f(bch(hv.w), bch(udr[4*q+3]), acc);
  }
  return acc;
}

__device__ __forceinline__ half8 cvt8(f4v a, f4v b){
  half8 h;
  h[0]=(_Float16)a.x; h[1]=(_Float16)a.y; h[2]=(_Float16)a.z; h[3]=(_Float16)a.w;
  h[4]=(_Float16)b.x; h[5]=(_Float16)b.y; h[6]=(_Float16)b.z; h[7]=(_Float16)b.w;
  return h;
}

// ============ Kernel A: encoder — 8 elems/block, grid 512 (R15) ============
// R14 post-mortem: grid 256 put ONE 4-wave block per CU = 1 wave/SIMD; the
// per-step __syncthreads exposed every barrier/MFMA/LDS latency (enc occupancy
// 2.9%). R15: 8 elements/block (MFMA columns 8..15 idle — MFMA count is
// unchanged and cheap), grid 512 -> 2 blocks/CU -> 2 waves/SIMD so one
// block's barrier bubbles are covered by the other. Stores guarded c<8.
// hpG layout identical (decoder unchanged/proven).
__global__ __launch_bounds__(256, 1)
void darnn_enc(const float* __restrict__ x,
               const float* __restrict__ W_ih_e, const float* __restrict__ W_hh_e,
               const float* __restrict__ b_ih_e, const float* __restrict__ b_hh_e,
               const float* __restrict__ U_d, const float* __restrict__ W_out,
               unsigned* __restrict__ hpG, float* __restrict__ hTG)
{
  const int tid = threadIdx.x;
  const int w = tid >> 6;        // wave 0..3: owns hidden units [16w,16w+16)
  const int l = tid & 63;
  const int c = l & 15;          // MFMA column = element slot (0..7 live)
  const int q = l >> 4;          // quad
  const int e0 = blockIdx.x * 8;
  const int m0 = 16*w + 4*q;     // first of this lane's 4 hidden units

  __shared__ __align__(16) _Float16 He[2][16*72]; // ping-pong h[e][k], pad 72
  __shared__ __align__(16) unsigned xw[16*65];    // x fp16-pairs [e][65]

  // ---- stage x (only 8 live elements) + zero He[0] ----
  for (int idx = tid; idx < 8*64; idx += 256) {
    int e = idx >> 6, j = idx & 63;
    f2 g = ((const f2*)(x + (size_t)(e0+e)*T))[j];
    xw[e*65 + j] = pk2(g.x, g.y);
  }
  for (int idx = tid; idx < 576; idx += 256) ((unsigned*)He[0])[idx] = 0;

  // ---- A-frags: this wave's W_hh rows (r/z/n) ----
  half8 Ar[2], Az[2], An[2];
  #pragma unroll
  for (int kap = 0; kap < 2; ++kap) {
    const f4v* pr = (const f4v*)(W_hh_e + (size_t)(16*w + c)*64       + 32*kap + 8*q);
    const f4v* pz = (const f4v*)(W_hh_e + (size_t)(64 + 16*w + c)*64  + 32*kap + 8*q);
    const f4v* pn = (const f4v*)(W_hh_e + (size_t)(128 + 16*w + c)*64 + 32*kap + 8*q);
    Ar[kap] = cvt8(pr[0], pr[1]);
    Az[kap] = cvt8(pz[0], pz[1]);
    An[kap] = cvt8(pn[0], pn[1]);
  }
  // ---- Hp/hw A-frags: wave0/1 -> U_d rows (xC2), wave2 -> W_out2 ----
  half8 AX[2] = {{0,0,0,0,0,0,0,0},{0,0,0,0,0,0,0,0}};
  if (w < 2) {
    #pragma unroll
    for (int kap = 0; kap < 2; ++kap) {
      const f4v* p = (const f4v*)(U_d + (size_t)(16*w + c)*64 + 32*kap + 8*q);
      AX[kap] = cvt8(p[0] * C2, p[1] * C2);
    }
  } else if (w == 2 && c == 0) {
    #pragma unroll
    for (int kap = 0; kap < 2; ++kap) {
      const f4v* p = (const f4v*)(W_out + 64 + 32*kap + 8*q);
      AX[kap] = cvt8(p[0], p[1]);
    }
  }
  // ---- per-lane combine params for m0..m0+3 ----
  f4v wih0 = *(const f4v*)(W_ih_e + m0);
  f4v wih1 = *(const f4v*)(W_ih_e + 64 + m0);
  f4v wih2 = *(const f4v*)(W_ih_e + 128 + m0);
  f4v bb0  = *(const f4v*)(b_ih_e + m0)      + *(const f4v*)(b_hh_e + m0);
  f4v bb1  = *(const f4v*)(b_ih_e + 64 + m0) + *(const f4v*)(b_hh_e + 64 + m0);
  f4v bi2  = *(const f4v*)(b_ih_e + 128 + m0);
  f4v bh2  = *(const f4v*)(b_hh_e + 128 + m0);
  f4v hreg = {0,0,0,0};
  const f4v z4 = {0,0,0,0};
  unsigned* hpB = hpG + (size_t)(e0 + c) * 2176;   // valid only for c<8

  __syncthreads();

  // ---- 128 steps: read He[t&1], write He[(t+1)&1], 1 barrier/step ----
  #pragma unroll 1
  for (int t = 0; t < T; ++t) {
    const _Float16* Hc = He[t & 1];
    half8 B0 = __builtin_bit_cast(half8, *(const uint4*)(Hc + c*72 + 8*q));
    half8 B1 = __builtin_bit_cast(half8, *(const uint4*)(Hc + c*72 + 32 + 8*q));
    if (t > 0) {           // Hp/hw for t-1 from h_{t-1} (= the B-frags)
      if (w < 2) {
        f4v cu = __builtin_amdgcn_mfma_f32_16x16x32_f16(AX[0], B0, z4, 0,0,0);
        cu     = __builtin_amdgcn_mfma_f32_16x16x32_f16(AX[1], B1, cu, 0,0,0);
        if (c < 8) {
          unsigned* hpE = hpB + (t-1)*17 + 8*w;
          hpE[2*q]   = pk2(cu[0], cu[1]);
          hpE[2*q+1] = pk2(cu[2], cu[3]);
        }
      } else if (w == 2) {
        f4v cw = __builtin_amdgcn_mfma_f32_16x16x32_f16(AX[0], B0, z4, 0,0,0);
        cw     = __builtin_amdgcn_mfma_f32_16x16x32_f16(AX[1], B1, cw, 0,0,0);
        if (q == 0 && c < 8) ((float*)(hpB + (t-1)*17))[16] = cw[0];
      }
    }
    f4v gr = __builtin_amdgcn_mfma_f32_16x16x32_f16(Ar[0], B0, z4, 0,0,0);
    gr     = __builtin_amdgcn_mfma_f32_16x16x32_f16(Ar[1], B1, gr, 0,0,0);
    f4v gz = __builtin_amdgcn_mfma_f32_16x16x32_f16(Az[0], B0, z4, 0,0,0);
    gz     = __builtin_amdgcn_mfma_f32_16x16x32_f16(Az[1], B1, gz, 0,0,0);
    f4v gn = __builtin_amdgcn_mfma_f32_16x16x32_f16(An[0], B0, z4, 0,0,0);
    gn     = __builtin_amdgcn_mfma_f32_16x16x32_f16(An[1], B1, gn, 0,0,0);
    float xc = (float)((const _Float16*)xw)[c*130 + t];
    f4v hn;
    #pragma unroll
    for (int i = 0; i < 4; ++i) {
      float r  = fsig(fmaf(xc, wih0[i], bb0[i]) + gr[i]);
      float zf = fsig(fmaf(xc, wih1[i], bb1[i]) + gz[i]);
      float n  = ftanh(fmaf(xc, wih2[i], bi2[i]) + r*(gn[i] + bh2[i]));
      float h  = fmaf(zf, hreg[i] - n, n);
      hreg[i] = h;
      hn[i] = h;
    }
    uint2 wv; wv.x = pk2(hn[0], hn[1]); wv.y = pk2(hn[2], hn[3]);
    *(uint2*)(He[(t+1)&1] + c*72 + m0) = wv;
    __syncthreads();
  }
  // ---- epilogue: Hp/hw for t=127 from He[0] (= h_127) ----
  {
    const _Float16* Hc = He[0];
    half8 B0 = __builtin_bit_cast(half8, *(const uint4*)(Hc + c*72 + 8*q));
    half8 B1 = __builtin_bit_cast(half8, *(const uint4*)(Hc + c*72 + 32 + 8*q));
    if (w < 2) {
      f4v cu = __builtin_amdgcn_mfma_f32_16x16x32_f16(AX[0], B0, z4, 0,0,0);
      cu     = __builtin_amdgcn_mfma_f32_16x16x32_f16(AX[1], B1, cu, 0,0,0);
      if (c < 8) {
        unsigned* hpE = hpB + 127*17 + 8*w;
        hpE[2*q]   = pk2(cu[0], cu[1]);
        hpE[2*q+1] = pk2(cu[2], cu[3]);
      }
    } else if (w == 2) {
      f4v cw = __builtin_amdgcn_mfma_f32_16x16x32_f16(AX[0], B0, z4, 0,0,0);
      cw     = __builtin_amdgcn_mfma_f32_16x16x32_f16(AX[1], B1, cw, 0,0,0);
      if (q == 0 && c < 8) ((float*)(hpB + 127*17))[16] = cw[0];
    }
  }
  // ---- h_T (fp32) ----
  if (c < 8) {
    #pragma unroll
    for (int i = 0; i < 4; ++i)
      hTG[(size_t)(e0 + c)*64 + m0 + i] = hreg[i];
  }
}

// ============ Kernel B: decoder — PROVEN R13/R14 decoder, unchanged ========
__global__ __launch_bounds__(128, 2)
void darnn_dec(const float* __restrict__ W_init, const float* __restrict__ b_init,
               const float* __restrict__ W_ih_d, const float* __restrict__ W_hh_d,
               const float* __restrict__ b_ih_d, const float* __restrict__ b_hh_d,
               const float* __restrict__ W_d, const float* __restrict__ v_d,
               const float* __restrict__ W_out, const float* __restrict__ b_out,
               const float* __restrict__ y0,
               const unsigned* __restrict__ hpG, const float* __restrict__ hTG,
               float* __restrict__ out)
{
  const int tid = threadIdx.x;
  const int wid = tid >> 6;
  const int l   = tid & 63;
  const int b   = 2*blockIdx.x + wid;
  const int a    = l & 31;
  const int half = l >> 5;

  __shared__ __align__(16) unsigned char smem[18496];
  unsigned char* wbp = smem + wid*9248;
  unsigned* sh_hp   = (unsigned*)wbp;
  _Float16* sh_ring = (_Float16*)(wbp + 8704);
  float*    sh_hT   = (float*)(wbp + 8864);
  float*    sh_dp   = (float*)(wbp + 9120);

  {
    const uint4* src = (const uint4*)(hpG + (size_t)b * 2176);
    #pragma unroll
    for (int it = 0; it < 8; ++it)
      ((uint4*)sh_hp)[it*64 + l] = src[it*64 + l];
    const unsigned* s2 = hpG + (size_t)b*2176 + 2048;
    sh_hp[2048 + l] = s2[l];
    sh_hp[2112 + l] = s2[64 + l];
  }
  sh_hT[l] = hTG[(size_t)b*64 + l];

  unsigned wr_r[32], wr_z[32], wr_n[32];
  {
    const f4v* wp = (const f4v*)W_hh_d;
    #pragma unroll
    for (int k = 0; k < 16; ++k) {
      f4v vr = wp[l*16 + k];
      f4v vz = wp[(64 + l)*16 + k];
      f4v vn = wp[(128 + l)*16 + k];
      wr_r[2*k] = pk2(vr.x, vr.y); wr_r[2*k+1] = pk2(vr.z, vr.w);
      wr_z[2*k] = pk2(vz.x, vz.y); wr_z[2*k+1] = pk2(vz.z, vz.w);
      wr_n[2*k] = pk2(vn.x, vn.y); wr_n[2*k+1] = pk2(vn.z, vn.w);
    }
  }
  float wih0 = W_ih_d[l], wih1 = W_ih_d[64+l], wih2 = W_ih_d[128+l];
  float bb0  = b_ih_d[l] + b_hh_d[l];
  float bb1  = b_ih_d[64+l] + b_hh_d[64+l];
  float bih2 = b_ih_d[128+l], bhh2 = b_hh_d[128+l];
  unsigned udr[16];
  {
    const f2* up = (const f2*)(W_d + a*64 + half*32);
    #pragma unroll
    for (int k = 0; k < 16; ++k) { f2 f = up[k]; udr[k] = pk2(f.x, f.y); }
  }
  float dprev;
  {
    const f4v* wi = (const f4v*)(W_init + l*64);
    const f4v* hb = (const f4v*)sh_hT;
    f2 a0={0,0}, a1={0,0};
    #pragma unroll
    for (int k = 0; k < 16; ++k) {
      f4v wv = wi[k]; f4v hv = hb[k];
      a0 = pkfma(wv.xy, hv.xy, a0);
      a1 = pkfma(wv.zw, hv.zw, a1);
    }
    dprev = b_init[l] + (a0.x + a0.y) + (a1.x + a1.y);
  }
  float wout1 = W_out[l];
  float hw0 = __builtin_bit_cast(float, sh_hp[l*17 + 16]);
  float hw1 = __builtin_bit_cast(float, sh_hp[(64 + l)*17 + 16]);
  float oprev = y0[0];
  float bo = b_out[0];
  float c1;
  {
    float sv = v_d[a];
    sv += __shfl_xor(sv, 16); sv += __shfl_xor(sv, 8);
    sv += __shfl_xor(sv, 4);  sv += __shfl_xor(sv, 2); sv += __shfl_xor(sv, 1);
    c1 = LOG2E * sv;
  }
  sh_ring[l] = (_Float16)dprev;

  const unsigned* hpr0 = sh_hp + l*17;
  const unsigned* hpr1 = sh_hp + (64 + l)*17;

  #pragma unroll 1
  for (int s = 0; s < HOR; ++s) {
    float ar0=0,ar1=0,az0=0,az1=0,an0=0,an1=0;
    gru_mv(sh_ring, wr_r, wr_z, wr_n, ar0,ar1,az0,az1,an0,an1);
    float r = fsig(fmaf(oprev, wih0, bb0) + ar0 + ar1);
    float z = fsig(fmaf(oprev, wih1, bb1) + az0 + az1);
    float n = ftanh(fmaf(oprev, wih2, bih2) + r * (an0 + an1 + bhh2));
    float dnew = fmaf(z, dprev - n, n);
    dprev = dnew;
    sh_ring[l] = (_Float16)dnew;
    {
      float acc = proj_dot(sh_ring + half*32, udr);
      acc += __shfl_xor(acc, 32);
      if (l < 32) sh_dp[l] = C2 * acc;
    }
    float rs0 = 0.f, rs1 = 0.f;
    #pragma unroll
    for (int j2 = 0; j2 < 8; ++j2) {
      f4v dp = *(const f4v*)&sh_dp[4*j2];
      half2_t ha0 = bch(hpr0[2*j2]), hb0 = bch(hpr0[2*j2+1]);
      half2_t ha1 = bch(hpr1[2*j2]), hb1 = bch(hpr1[2*j2+1]);
      float v0 = v_d[4*j2], v1 = v_d[4*j2+1], v2 = v_d[4*j2+2], v3 = v_d[4*j2+3];
      rs0 = fmaf(v0, frcp(1.0f + fexp2(dp.x + (float)ha0.x)), rs0);
      rs0 = fmaf(v1, frcp(1.0f + fexp2(dp.y + (float)ha0.y)), rs0);
      rs0 = fmaf(v2, frcp(1.0f + fexp2(dp.z + (float)hb0.x)), rs0);
      rs0 = fmaf(v3, frcp(1.0f + fexp2(dp.w + (float)hb0.y)), rs0);
      rs1 = fmaf(v0, frcp(1.0f + fexp2(dp.x + (float)ha1.x)), rs1);
      rs1 = fmaf(v1, frcp(1.0f + fexp2(dp.y + (float)ha1.y)), rs1);
      rs1 = fmaf(v2, frcp(1.0f + fexp2(dp.z + (float)hb1.x)), rs1);
      rs1 = fmaf(v3, frcp(1.0f + fexp2(dp.w + (float)hb1.y)), rs1);
    }
    float e0 = fexp2(fmaf(-C2, rs0, c1));
    float e1 = fexp2(fmaf(-C2, rs1, c1));
    float P0 = rdl63(wavesum_dpp(e0 + e1));
    float P1 = rdl63(wavesum_dpp(fmaf(e0, hw0, e1 * hw1)));
    float P2 = rdl63(wavesum_dpp(wout1 * dnew));
    float o = fmaf(P1, frcp(P0), P2 + bo);
    if (l == 0) out[(size_t)b * HOR + s] = o;
    oprev = o;
  }
}

extern "C" void kernel_launch(void* const* d_in, const int* in_sizes, int n_in,
                              void* d_out, int out_size, void* d_ws, size_t ws_size,
                              hipStream_t stream) {
  const float* x      = (const float*)d_in[0];
  const float* W_ih_e = (const float*)d_in[1];
  const float* W_hh_e = (const float*)d_in[2];
  const float* b_ih_e = (const float*)d_in[3];
  const float* b_hh_e = (const float*)d_in[4];
  // d_in[5..8] = W_e, U_e, b_e, v_e : dead (softmax over size-1 axis == 1)
  const float* W_init = (const float*)d_in[9];
  const float* b_init = (const float*)d_in[10];
  const float* W_ih_d = (const float*)d_in[11];
  const float* W_hh_d = (const float*)d_in[12];
  const float* b_ih_d = (const float*)d_in[13];
  const float* b_hh_d = (const float*)d_in[14];
  const float* W_d    = (const float*)d_in[15];
  const float* U_d    = (const float*)d_in[16];
  const float* v_d    = (const float*)d_in[17];
  const float* W_out  = (const float*)d_in[18];
  const float* b_out  = (const float*)d_in[19];
  const float* y0     = (const float*)d_in[20];
  float* outp = (float*)d_out;

  unsigned* hpG = (unsigned*)d_ws;
  float*    hTG = (float*)((char*)d_ws + (size_t)BATCH * 2176 * 4);

  darnn_enc<<<BATCH/8, 256, 0, stream>>>(x, W_ih_e, W_hh_e, b_ih_e, b_hh_e,
      U_d, W_out, hpG, hTG);
  darnn_dec<<<BATCH/2, 128, 0, stream>>>(W_init, b_init, W_ih_d, W_hh_d,
      b_ih_d, b_hh_d, W_d, v_d, W_out, b_out, y0, hpG, hTG, outp);
}